// Round 7
// baseline (423.377 us; speedup 1.0000x reference)
//
#include <hip/hip_runtime.h>

// Fused: embed blocks [0,embed_blocks) + per-block bucket histogram blocks.
// Count part writes PRIVATE pcount[jb][b] rows -> no global atomics, no memset.
__global__ __launch_bounds__(256) void embed_count_kernel(
    const int* __restrict__ x, const float* __restrict__ emb, float* __restrict__ h0,
    const int* __restrict__ ei, int* __restrict__ pcount,
    int n_nodes, int n_edges, int n_bkt, int embed_blocks)
{
    __shared__ int cnt[512];
    int t = threadIdx.x;
    if ((int)blockIdx.x < embed_blocks) {
        int tt = blockIdx.x * 256 + t;
        if (tt < n_nodes * 16) {
            int n = tt >> 4, q = tt & 15;
            int xv = x[n];
            float4 v = {0.f, 0.f, 0.f, 0.f};
            if (xv != 0) v = *(const float4*)(emb + (size_t)xv * 64 + q * 4);
            *(float4*)(h0 + (size_t)n * 64 + q * 4) = v;
        }
        return;
    }
    int jb = blockIdx.x - embed_blocks;
    for (int b = t; b < 512; b += 256) cnt[b] = 0;
    __syncthreads();
    int base = jb * 8192;
#pragma unroll
    for (int i = 0; i < 32; ++i) {
        int e = base + i * 256 + t;
        if (e < n_edges) atomicAdd(&cnt[ei[n_edges + e] >> 7], 1);
    }
    __syncthreads();
    for (int b = t; b < n_bkt; b += 256) pcount[jb * n_bkt + b] = cnt[b];
}

// Each scatter block deterministically derives bucket_start (scan of column
// sums of pcount) AND its own per-bucket base (prefix over earlier blocks):
// no global atomics, no bucket_fill. Block 0 publishes bucket_start for sort.
// Payload: src(16) | r<<16 | dstlo<<18.
__global__ __launch_bounds__(256) void scatter_kernel(
    const int* __restrict__ ei, const int* __restrict__ et,
    const int* __restrict__ pcount, int* __restrict__ esort,
    int* __restrict__ bucket_start_g, int* __restrict__ rowstartR,
    int n_edges, int n_bkt, int n_cblk, int n_nodes)
{
    __shared__ int tot[512], myb[512], fill2[512], ps[256];
    int t = threadIdx.x, j = blockIdx.x;
    for (int b = t; b < 512; b += 256) { tot[b] = 0; myb[b] = 0; fill2[b] = 0; }
    __syncthreads();
    for (int b = t; b < n_bkt; b += 256) {
        int tt = 0, pre = 0;
        for (int jj = 0; jj < n_cblk; ++jj) {
            int v = pcount[jj * n_bkt + b];
            tt += v;
            pre += (jj < j) ? v : 0;
        }
        tot[b] = tt;
        myb[b] = pre;
    }
    __syncthreads();
    int a0 = tot[2 * t], a1 = tot[2 * t + 1];
    ps[t] = a0 + a1;
    __syncthreads();
    for (int o = 1; o < 256; o <<= 1) {
        int v = (t >= o) ? ps[t - o] : 0;
        __syncthreads();
        ps[t] += v;
        __syncthreads();
    }
    int base = (t > 0) ? ps[t - 1] : 0;
    int s0 = base, s1 = base + a0;
    if (j == 0) {
        if (2 * t < n_bkt)     bucket_start_g[2 * t] = s0;
        if (2 * t + 1 < n_bkt) bucket_start_g[2 * t + 1] = s1;
        if (t == 0) { bucket_start_g[n_bkt] = n_edges; rowstartR[4 * n_nodes] = n_edges; }
    }
    tot[2 * t] = s0; tot[2 * t + 1] = s1;
    __syncthreads();
    for (int b = t; b < n_bkt; b += 256) myb[b] += tot[b];
    __syncthreads();
    int basee = j * 8192;
#pragma unroll
    for (int i = 0; i < 32; ++i) {
        int e = basee + i * 256 + t;
        if (e < n_edges) {
            int s = ei[e], d = ei[n_edges + e], r = et[e];
            int b = d >> 7;
            int pos = myb[b] + atomicAdd(&fill2[b], 1);
            esort[pos] = s | (r << 16) | ((d & 127) << 18);
        }
    }
}

// one block per bucket: 512-bin counting sort (bin = dstlo*4 + r) -> edges
// grouped by (dst, rel); emits rowstartR[dst*4 + r].
__global__ __launch_bounds__(256) void bucket_sort_kernel(
    const int* __restrict__ bucket_start, int* __restrict__ esort,
    int* __restrict__ scratch, int* __restrict__ rowstartR, int n_nodes)
{
    __shared__ int cnt[512], off[512], fill[512], ps[256];
    int t = threadIdx.x, b = blockIdx.x;
    int s = bucket_start[b], e = bucket_start[b + 1];
    cnt[t] = 0; cnt[t + 256] = 0; fill[t] = 0; fill[t + 256] = 0;
    __syncthreads();
    int* scr = scratch + (size_t)b * 8192;
    for (int i = s + t; i < e; i += 256) {
        int p = esort[i];
        scr[i - s] = p;
        atomicAdd(&cnt[(p >> 16) & 0x1FF], 1);
    }
    __syncthreads();
    int a0 = cnt[2 * t], a1 = cnt[2 * t + 1];
    ps[t] = a0 + a1;
    __syncthreads();
    for (int o = 1; o < 256; o <<= 1) {
        int v = (t >= o) ? ps[t - o] : 0;
        __syncthreads();
        ps[t] += v;
        __syncthreads();
    }
    int basex = (t > 0) ? ps[t - 1] : 0;
    off[2 * t] = basex;
    off[2 * t + 1] = basex + a0;
    __syncthreads();
    int d0 = b * 128 + (2 * t >> 2);
    if (d0 < n_nodes) rowstartR[b * 512 + 2 * t] = s + off[2 * t];
    int d1 = b * 128 + ((2 * t + 1) >> 2);
    if (d1 < n_nodes) rowstartR[b * 512 + 2 * t + 1] = s + off[2 * t + 1];
    __syncthreads();
    for (int i = s + t; i < e; i += 256) {
        int p = scr[i - s];
        int bin = (p >> 16) & 0x1FF;
        int pos = s + off[bin] + atomicAdd(&fill[bin], 1);
        esort[pos] = p;
    }
}

// one wave per dst; edges pre-grouped by rel -> 3 mask-free sub-ranges.
__global__ __launch_bounds__(256) void agg_kernel(
    const float* __restrict__ hin, const int* __restrict__ rowstartR,
    const int* __restrict__ esort, float* __restrict__ means, int n_nodes)
{
    int wid = (blockIdx.x * 256 + threadIdx.x) >> 6;
    int lane = threadIdx.x & 63;
    if (wid >= n_nodes) return;
    int q = lane >> 4;
    int c = lane & 15;
    int4 rs = *(const int4*)(rowstartR + wid * 4);

#pragma unroll
    for (int r = 0; r < 3; ++r) {
        int sR = (r == 0) ? rs.x : (r == 1) ? rs.y : rs.z;
        int eR = (r == 0) ? rs.y : (r == 1) ? rs.z : rs.w;
        float4 a = {0.f, 0.f, 0.f, 0.f};
        for (int i = sR + q; i < eR; i += 4) {
            int p = esort[i];
            float4 v = *(const float4*)(hin + (size_t)(p & 0xFFFF) * 64 + c * 4);
            a.x += v.x; a.y += v.y; a.z += v.z; a.w += v.w;
        }
        a.x += __shfl_xor(a.x, 16); a.y += __shfl_xor(a.y, 16);
        a.z += __shfl_xor(a.z, 16); a.w += __shfl_xor(a.w, 16);
        a.x += __shfl_xor(a.x, 32); a.y += __shfl_xor(a.y, 32);
        a.z += __shfl_xor(a.z, 32); a.w += __shfl_xor(a.w, 32);
        if (q == r) {
            float inv = 1.f / (float)max(eR - sR, 1);
            float4 m = {a.x * inv, a.y * inv, a.z * inv, a.w * inv};
            *(float4*)(means + (size_t)wid * 192 + r * 64 + c * 4) = m;
        }
    }
}

// thread = (4-node group, j-quad). W streamed through LDS in 4 slabs of 64
// rows (16 KB), double-buffered (32 KB total -> 5 blocks/CU, ~12 waves/CU
// co-resident vs 8 with the 64 KB full-W version). Slab 0 = wroot,
// slabs 1..3 = wrel. Next slab staged while computing the current one.
__global__ __launch_bounds__(256) void transform_kernel(
    const float* __restrict__ hin, const float* __restrict__ means,
    const float* __restrict__ wroot, const float* __restrict__ wrel,
    const float* __restrict__ bias, float* __restrict__ hout, int n_nodes)
{
    __shared__ float wsh[2][4096];   // 2 x 16 KB
    int t = threadIdx.x;
    int gt = blockIdx.x * 256 + t;
    int g = gt >> 4, q = gt & 15;
    int n0 = g * 4;
    bool active = (n0 < n_nodes);

    // stage slab 0 (wroot)
    {
        const float4* sp = (const float4*)wroot;
        float4* d = (float4*)wsh[0];
#pragma unroll
        for (int i = 0; i < 4; ++i) d[t + i * 256] = sp[t + i * 256];
    }

    float4 acc[4];
    float4 b = {0.f, 0.f, 0.f, 0.f};
    if (active) b = *(const float4*)(bias + q * 4);
#pragma unroll
    for (int i = 0; i < 4; ++i) acc[i] = b;

    const float* hv = hin + (size_t)n0 * 64;
    const float* mv = means + (size_t)n0 * 192;

    for (int s = 0; s < 4; ++s) {
        __syncthreads();   // slab s staged; buffer (s+1)&1 free (compute s-1 done)
        if (s < 3) {
            const float4* sp = (const float4*)wrel + (size_t)s * 1024;
            float4* d = (float4*)wsh[(s + 1) & 1];
#pragma unroll
            for (int i = 0; i < 4; ++i) d[t + i * 256] = sp[t + i * 256];
        }
        const float* vbase = (s == 0) ? hv : (mv + (s - 1) * 64);
        int vstride = (s == 0) ? 64 : 192;
        const float* wbuf = wsh[s & 1];
        if (active) {
#pragma unroll 4
            for (int k4 = 0; k4 < 16; ++k4) {
                float4 v[4];
#pragma unroll
                for (int i = 0; i < 4; ++i)
                    v[i] = *(const float4*)(vbase + i * vstride + k4 * 4);
#pragma unroll
                for (int kk = 0; kk < 4; ++kk) {
                    float4 w = *(const float4*)(wbuf + (k4 * 4 + kk) * 64 + q * 4);
#pragma unroll
                    for (int i = 0; i < 4; ++i) {
                        float sv = kk == 0 ? v[i].x : kk == 1 ? v[i].y : kk == 2 ? v[i].z : v[i].w;
                        acc[i].x = fmaf(sv, w.x, acc[i].x);
                        acc[i].y = fmaf(sv, w.y, acc[i].y);
                        acc[i].z = fmaf(sv, w.z, acc[i].z);
                        acc[i].w = fmaf(sv, w.w, acc[i].w);
                    }
                }
            }
        }
    }
    if (active) {
        float* o = hout + (size_t)n0 * 64 + q * 4;
#pragma unroll
        for (int i = 0; i < 4; ++i) {
            float4 r = {fmaxf(acc[i].x, 0.f), fmaxf(acc[i].y, 0.f),
                        fmaxf(acc[i].z, 0.f), fmaxf(acc[i].w, 0.f)};
            *(float4*)(o + i * 64) = r;
        }
    }
}

// wave per graph: batch sorted -> binary-search bounds, mean, then 64->2 head
__global__ __launch_bounds__(256) void pool_kernel(
    const float* __restrict__ h2, const int* __restrict__ batch,
    const float* __restrict__ linw, const float* __restrict__ linb,
    float* __restrict__ out, int n_nodes, int n_graphs)
{
    int wid = (blockIdx.x * 256 + threadIdx.x) >> 6;
    int lane = threadIdx.x & 63;
    if (wid >= n_graphs) return;
    int g = wid;
    int lo = 0, hi = n_nodes;
    while (lo < hi) { int mid = (lo + hi) >> 1; if (batch[mid] < g) lo = mid + 1; else hi = mid; }
    int s = lo;
    lo = 0; hi = n_nodes;
    while (lo < hi) { int mid = (lo + hi) >> 1; if (batch[mid] < g + 1) lo = mid + 1; else hi = mid; }
    int e = lo;
    float sum = 0.f;
    for (int n = s; n < e; ++n) sum += h2[(size_t)n * 64 + lane];
    float mean = sum / (float)max(e - s, 1);
    float d0 = mean * linw[lane * 2 + 0];
    float d1 = mean * linw[lane * 2 + 1];
    for (int off = 32; off > 0; off >>= 1) {
        d0 += __shfl_down(d0, off);
        d1 += __shfl_down(d1, off);
    }
    if (lane == 0) {
        out[g * 2 + 0] = d0 + linb[0];
        out[g * 2 + 1] = d1 + linb[1];
    }
}

extern "C" void kernel_launch(void* const* d_in, const int* in_sizes, int n_in,
                              void* d_out, int out_size, void* d_ws, size_t ws_size,
                              hipStream_t stream)
{
    const int*   x      = (const int*)d_in[0];
    const int*   ei     = (const int*)d_in[1];
    const int*   et     = (const int*)d_in[2];
    const int*   batch  = (const int*)d_in[3];
    const float* emb    = (const float*)d_in[4];
    const float* w1rel  = (const float*)d_in[5];
    const float* w1root = (const float*)d_in[6];
    const float* b1     = (const float*)d_in[7];
    const float* w2rel  = (const float*)d_in[8];
    const float* w2root = (const float*)d_in[9];
    const float* b2     = (const float*)d_in[10];
    const float* linw   = (const float*)d_in[11];
    const float* linb   = (const float*)d_in[12];
    float* out = (float*)d_out;

    const int N = in_sizes[0];         // 50000
    const int E = in_sizes[2];         // 1250000
    const int G = out_size / 2;        // 512
    const int NBKT = (N + 127) >> 7;   // 391
    const int NCBLK = (E + 8191) / 8192;  // 153

    // workspace layout (~70 MB)
    float* hA        = (float*)d_ws;                     // [N][64]
    float* hB        = hA + (size_t)N * 64;              // [N][64]
    float* means     = hB + (size_t)N * 64;              // [N][192]; head doubles as sort scratch
    int*   esort     = (int*)(means + (size_t)N * 192);  // [E]
    int*   rowstartR = esort + E;                        // [4N+4]
    int*   bucket_start = rowstartR + 4 * N + 4;         // [NBKT+1]
    int*   pcount    = bucket_start + NBKT + 1;          // [NCBLK*NBKT]

    int embedBlocks = (N * 16 + 255) / 256;              // 3125
    embed_count_kernel<<<embedBlocks + NCBLK, 256, 0, stream>>>(
        x, emb, hA, ei, pcount, N, E, NBKT, embedBlocks);
    scatter_kernel<<<NCBLK, 256, 0, stream>>>(
        ei, et, pcount, esort, bucket_start, rowstartR, E, NBKT, NCBLK, N);
    bucket_sort_kernel<<<NBKT, 256, 0, stream>>>(bucket_start, esort, (int*)means, rowstartR, N);

    int aggBlocks = (N * 64 + 255) / 256;                // one wave per dst
    int tfBlocks  = ((N + 3) / 4 * 16 + 255) / 256;      // 4 nodes per thread
    agg_kernel<<<aggBlocks, 256, 0, stream>>>(hA, rowstartR, esort, means, N);
    transform_kernel<<<tfBlocks, 256, 0, stream>>>(hA, means, w1root, w1rel, b1, hB, N);
    agg_kernel<<<aggBlocks, 256, 0, stream>>>(hB, rowstartR, esort, means, N);
    transform_kernel<<<tfBlocks, 256, 0, stream>>>(hB, means, w2root, w2rel, b2, hA, N);

    pool_kernel<<<(G * 64 + 255) / 256, 256, 0, stream>>>(hA, batch, linw, linb, out, N, G);
}

// Round 8
// 349.146 us; speedup vs baseline: 1.2126x; 1.2126x over previous
//
#include <hip/hip_runtime.h>

#define CHUNK 2048

// Fused: embed blocks [0,embed_blocks) + per-chunk bucket histogram blocks.
// Count part writes PRIVATE pcount[chunk][b] rows -> no global atomics.
__global__ __launch_bounds__(256) void embed_count_kernel(
    const int* __restrict__ x, const float* __restrict__ emb, float* __restrict__ h0,
    const int* __restrict__ ei, int* __restrict__ pcount,
    int n_nodes, int n_edges, int n_bkt, int embed_blocks)
{
    __shared__ int cnt[512];
    int t = threadIdx.x;
    if ((int)blockIdx.x < embed_blocks) {
        int tt = blockIdx.x * 256 + t;
        if (tt < n_nodes * 16) {
            int n = tt >> 4, q = tt & 15;
            int xv = x[n];
            float4 v = {0.f, 0.f, 0.f, 0.f};
            if (xv != 0) v = *(const float4*)(emb + (size_t)xv * 64 + q * 4);
            *(float4*)(h0 + (size_t)n * 64 + q * 4) = v;
        }
        return;
    }
    int jb = blockIdx.x - embed_blocks;
    for (int b = t; b < 512; b += 256) cnt[b] = 0;
    __syncthreads();
    int base = jb * CHUNK;
#pragma unroll
    for (int i = 0; i < CHUNK / 256; ++i) {
        int e = base + i * 256 + t;
        if (e < n_edges) atomicAdd(&cnt[ei[n_edges + e] >> 7], 1);
    }
    __syncthreads();
    for (int b = t; b < n_bkt; b += 256) pcount[jb * n_bkt + b] = cnt[b];
}

// one block per bucket: exclusive scan over the chunk counts of this bucket
// -> pre[chunk][b], and the bucket total -> totals[b]. (n_chk <= 1024)
__global__ __launch_bounds__(256) void colscan_kernel(
    const int* __restrict__ pcount, int* __restrict__ pre,
    int* __restrict__ totals, int n_chk, int n_bkt)
{
    __shared__ int ps[256];
    int b = blockIdx.x, t = threadIdx.x;
    int v[4], s = 0;
#pragma unroll
    for (int i = 0; i < 4; ++i) {
        int jj = t * 4 + i;
        v[i] = (jj < n_chk) ? pcount[jj * n_bkt + b] : 0;
        s += v[i];
    }
    ps[t] = s;
    __syncthreads();
    for (int o = 1; o < 256; o <<= 1) {
        int u = (t >= o) ? ps[t - o] : 0;
        __syncthreads();
        ps[t] += u;
        __syncthreads();
    }
    int run = (t > 0) ? ps[t - 1] : 0;
#pragma unroll
    for (int i = 0; i < 4; ++i) {
        int jj = t * 4 + i;
        if (jj < n_chk) pre[jj * n_bkt + b] = run;
        run += v[i];
    }
    if (t == 255) totals[b] = run;
}

// single block: exclusive scan of totals -> bucket_start[0..n_bkt]
__global__ __launch_bounds__(512) void scan_buckets_kernel(
    const int* __restrict__ totals, int* __restrict__ bucket_start,
    int* __restrict__ rowstartR, int n_bkt, int n_edges, int n_nodes)
{
    __shared__ int part[512];
    int t = threadIdx.x;
    part[t] = (t < n_bkt) ? totals[t] : 0;
    __syncthreads();
    for (int off = 1; off < 512; off <<= 1) {
        int v = (t >= off) ? part[t - off] : 0;
        __syncthreads();
        part[t] += v;
        __syncthreads();
    }
    if (t == 0) { bucket_start[0] = 0; rowstartR[4 * n_nodes] = n_edges; }
    if (t < n_bkt) bucket_start[t + 1] = part[t];
}

// 611 blocks x 2048 edges: deterministic per-(chunk,bucket) base from
// bucket_start + pre; only LDS fill atomics. Payload src | r<<16 | dstlo<<18.
__global__ __launch_bounds__(256) void scatter_kernel(
    const int* __restrict__ ei, const int* __restrict__ et,
    const int* __restrict__ pre, const int* __restrict__ bucket_start,
    int* __restrict__ esort, int n_edges, int n_bkt)
{
    __shared__ int myb[512], fill2[512];
    int t = threadIdx.x, j = blockIdx.x;
    for (int b = t; b < 512; b += 256) {
        myb[b] = (b < n_bkt) ? (bucket_start[b] + pre[j * n_bkt + b]) : 0;
        fill2[b] = 0;
    }
    __syncthreads();
    int base = j * CHUNK;
#pragma unroll
    for (int i = 0; i < CHUNK / 256; ++i) {
        int e = base + i * 256 + t;
        if (e < n_edges) {
            int s = ei[e], d = ei[n_edges + e], r = et[e];
            int b = d >> 7;
            int pos = myb[b] + atomicAdd(&fill2[b], 1);
            esort[pos] = s | (r << 16) | ((d & 127) << 18);
        }
    }
}

// one block per bucket: 512-bin counting sort (bin = dstlo*4 + r) -> edges
// grouped by (dst, rel); emits rowstartR[dst*4 + r].
__global__ __launch_bounds__(256) void bucket_sort_kernel(
    const int* __restrict__ bucket_start, int* __restrict__ esort,
    int* __restrict__ scratch, int* __restrict__ rowstartR, int n_nodes)
{
    __shared__ int cnt[512], off[512], fill[512], ps[256];
    int t = threadIdx.x, b = blockIdx.x;
    int s = bucket_start[b], e = bucket_start[b + 1];
    cnt[t] = 0; cnt[t + 256] = 0; fill[t] = 0; fill[t + 256] = 0;
    __syncthreads();
    int* scr = scratch + (size_t)b * 8192;
    for (int i = s + t; i < e; i += 256) {
        int p = esort[i];
        scr[i - s] = p;
        atomicAdd(&cnt[(p >> 16) & 0x1FF], 1);
    }
    __syncthreads();
    int a0 = cnt[2 * t], a1 = cnt[2 * t + 1];
    ps[t] = a0 + a1;
    __syncthreads();
    for (int o = 1; o < 256; o <<= 1) {
        int v = (t >= o) ? ps[t - o] : 0;
        __syncthreads();
        ps[t] += v;
        __syncthreads();
    }
    int basex = (t > 0) ? ps[t - 1] : 0;
    off[2 * t] = basex;
    off[2 * t + 1] = basex + a0;
    __syncthreads();
    int d0 = b * 128 + (2 * t >> 2);
    if (d0 < n_nodes) rowstartR[b * 512 + 2 * t] = s + off[2 * t];
    int d1 = b * 128 + ((2 * t + 1) >> 2);
    if (d1 < n_nodes) rowstartR[b * 512 + 2 * t + 1] = s + off[2 * t + 1];
    __syncthreads();
    for (int i = s + t; i < e; i += 256) {
        int p = scr[i - s];
        int bin = (p >> 16) & 0x1FF;
        int pos = s + off[bin] + atomicAdd(&fill[bin], 1);
        esort[pos] = p;
    }
}

// one wave per dst; edges pre-grouped by rel -> 3 mask-free sub-ranges.
__global__ __launch_bounds__(256) void agg_kernel(
    const float* __restrict__ hin, const int* __restrict__ rowstartR,
    const int* __restrict__ esort, float* __restrict__ means, int n_nodes)
{
    int wid = (blockIdx.x * 256 + threadIdx.x) >> 6;
    int lane = threadIdx.x & 63;
    if (wid >= n_nodes) return;
    int q = lane >> 4;
    int c = lane & 15;
    int4 rs = *(const int4*)(rowstartR + wid * 4);

#pragma unroll
    for (int r = 0; r < 3; ++r) {
        int sR = (r == 0) ? rs.x : (r == 1) ? rs.y : rs.z;
        int eR = (r == 0) ? rs.y : (r == 1) ? rs.z : rs.w;
        float4 a = {0.f, 0.f, 0.f, 0.f};
        for (int i = sR + q; i < eR; i += 4) {
            int p = esort[i];
            float4 v = *(const float4*)(hin + (size_t)(p & 0xFFFF) * 64 + c * 4);
            a.x += v.x; a.y += v.y; a.z += v.z; a.w += v.w;
        }
        a.x += __shfl_xor(a.x, 16); a.y += __shfl_xor(a.y, 16);
        a.z += __shfl_xor(a.z, 16); a.w += __shfl_xor(a.w, 16);
        a.x += __shfl_xor(a.x, 32); a.y += __shfl_xor(a.y, 32);
        a.z += __shfl_xor(a.z, 32); a.w += __shfl_xor(a.w, 32);
        if (q == r) {
            float inv = 1.f / (float)max(eR - sR, 1);
            float4 m = {a.x * inv, a.y * inv, a.z * inv, a.w * inv};
            *(float4*)(means + (size_t)wid * 192 + r * 64 + c * 4) = m;
        }
    }
}

// thread = (4-node group, j-quad). W streamed through LDS in 4 slabs of 64
// rows (16 KB), double-buffered (32 KB -> 5 blocks/CU).
__global__ __launch_bounds__(256) void transform_kernel(
    const float* __restrict__ hin, const float* __restrict__ means,
    const float* __restrict__ wroot, const float* __restrict__ wrel,
    const float* __restrict__ bias, float* __restrict__ hout, int n_nodes)
{
    __shared__ float wsh[2][4096];   // 2 x 16 KB
    int t = threadIdx.x;
    int gt = blockIdx.x * 256 + t;
    int g = gt >> 4, q = gt & 15;
    int n0 = g * 4;
    bool active = (n0 < n_nodes);

    {
        const float4* sp = (const float4*)wroot;
        float4* d = (float4*)wsh[0];
#pragma unroll
        for (int i = 0; i < 4; ++i) d[t + i * 256] = sp[t + i * 256];
    }

    float4 acc[4];
    float4 b = {0.f, 0.f, 0.f, 0.f};
    if (active) b = *(const float4*)(bias + q * 4);
#pragma unroll
    for (int i = 0; i < 4; ++i) acc[i] = b;

    const float* hv = hin + (size_t)n0 * 64;
    const float* mv = means + (size_t)n0 * 192;

    for (int s = 0; s < 4; ++s) {
        __syncthreads();
        if (s < 3) {
            const float4* sp = (const float4*)wrel + (size_t)s * 1024;
            float4* d = (float4*)wsh[(s + 1) & 1];
#pragma unroll
            for (int i = 0; i < 4; ++i) d[t + i * 256] = sp[t + i * 256];
        }
        const float* vbase = (s == 0) ? hv : (mv + (s - 1) * 64);
        int vstride = (s == 0) ? 64 : 192;
        const float* wbuf = wsh[s & 1];
        if (active) {
#pragma unroll 4
            for (int k4 = 0; k4 < 16; ++k4) {
                float4 v[4];
#pragma unroll
                for (int i = 0; i < 4; ++i)
                    v[i] = *(const float4*)(vbase + i * vstride + k4 * 4);
#pragma unroll
                for (int kk = 0; kk < 4; ++kk) {
                    float4 w = *(const float4*)(wbuf + (k4 * 4 + kk) * 64 + q * 4);
#pragma unroll
                    for (int i = 0; i < 4; ++i) {
                        float sv = kk == 0 ? v[i].x : kk == 1 ? v[i].y : kk == 2 ? v[i].z : v[i].w;
                        acc[i].x = fmaf(sv, w.x, acc[i].x);
                        acc[i].y = fmaf(sv, w.y, acc[i].y);
                        acc[i].z = fmaf(sv, w.z, acc[i].z);
                        acc[i].w = fmaf(sv, w.w, acc[i].w);
                    }
                }
            }
        }
    }
    if (active) {
        float* o = hout + (size_t)n0 * 64 + q * 4;
#pragma unroll
        for (int i = 0; i < 4; ++i) {
            float4 r = {fmaxf(acc[i].x, 0.f), fmaxf(acc[i].y, 0.f),
                        fmaxf(acc[i].z, 0.f), fmaxf(acc[i].w, 0.f)};
            *(float4*)(o + i * 64) = r;
        }
    }
}

// wave per graph: batch sorted -> binary-search bounds, mean, then 64->2 head
__global__ __launch_bounds__(256) void pool_kernel(
    const float* __restrict__ h2, const int* __restrict__ batch,
    const float* __restrict__ linw, const float* __restrict__ linb,
    float* __restrict__ out, int n_nodes, int n_graphs)
{
    int wid = (blockIdx.x * 256 + threadIdx.x) >> 6;
    int lane = threadIdx.x & 63;
    if (wid >= n_graphs) return;
    int g = wid;
    int lo = 0, hi = n_nodes;
    while (lo < hi) { int mid = (lo + hi) >> 1; if (batch[mid] < g) lo = mid + 1; else hi = mid; }
    int s = lo;
    lo = 0; hi = n_nodes;
    while (lo < hi) { int mid = (lo + hi) >> 1; if (batch[mid] < g + 1) lo = mid + 1; else hi = mid; }
    int e = lo;
    float sum = 0.f;
    for (int n = s; n < e; ++n) sum += h2[(size_t)n * 64 + lane];
    float mean = sum / (float)max(e - s, 1);
    float d0 = mean * linw[lane * 2 + 0];
    float d1 = mean * linw[lane * 2 + 1];
    for (int off = 32; off > 0; off >>= 1) {
        d0 += __shfl_down(d0, off);
        d1 += __shfl_down(d1, off);
    }
    if (lane == 0) {
        out[g * 2 + 0] = d0 + linb[0];
        out[g * 2 + 1] = d1 + linb[1];
    }
}

extern "C" void kernel_launch(void* const* d_in, const int* in_sizes, int n_in,
                              void* d_out, int out_size, void* d_ws, size_t ws_size,
                              hipStream_t stream)
{
    const int*   x      = (const int*)d_in[0];
    const int*   ei     = (const int*)d_in[1];
    const int*   et     = (const int*)d_in[2];
    const int*   batch  = (const int*)d_in[3];
    const float* emb    = (const float*)d_in[4];
    const float* w1rel  = (const float*)d_in[5];
    const float* w1root = (const float*)d_in[6];
    const float* b1     = (const float*)d_in[7];
    const float* w2rel  = (const float*)d_in[8];
    const float* w2root = (const float*)d_in[9];
    const float* b2     = (const float*)d_in[10];
    const float* linw   = (const float*)d_in[11];
    const float* linb   = (const float*)d_in[12];
    float* out = (float*)d_out;

    const int N = in_sizes[0];            // 50000
    const int E = in_sizes[2];            // 1250000
    const int G = out_size / 2;           // 512
    const int NBKT = (N + 127) >> 7;      // 391
    const int NCHK = (E + CHUNK - 1) / CHUNK;  // 611

    // workspace layout (~70 MB); pcount/pre live inside the means region
    // (beyond the 12.8 MB sort-scratch prefix), consumed before agg writes it.
    float* hA        = (float*)d_ws;                     // [N][64]
    float* hB        = hA + (size_t)N * 64;              // [N][64]
    float* means     = hB + (size_t)N * 64;              // [N][192]
    int*   esort     = (int*)(means + (size_t)N * 192);  // [E]
    int*   rowstartR = esort + E;                        // [4N+4]
    int*   bucket_start = rowstartR + 4 * N + 4;         // [NBKT+1]
    int*   totals    = bucket_start + NBKT + 1;          // [NBKT]
    int*   pcount    = (int*)means + 4 * 1024 * 1024;    // [NCHK*NBKT] (~1 MB)
    int*   pre       = (int*)means + 5 * 1024 * 1024;    // [NCHK*NBKT]

    int embedBlocks = (N * 16 + 255) / 256;              // 3125
    embed_count_kernel<<<embedBlocks + NCHK, 256, 0, stream>>>(
        x, emb, hA, ei, pcount, N, E, NBKT, embedBlocks);
    colscan_kernel<<<NBKT, 256, 0, stream>>>(pcount, pre, totals, NCHK, NBKT);
    scan_buckets_kernel<<<1, 512, 0, stream>>>(totals, bucket_start, rowstartR, NBKT, E, N);
    scatter_kernel<<<NCHK, 256, 0, stream>>>(ei, et, pre, bucket_start, esort, E, NBKT);
    bucket_sort_kernel<<<NBKT, 256, 0, stream>>>(bucket_start, esort, (int*)means, rowstartR, N);

    int aggBlocks = (N * 64 + 255) / 256;                // one wave per dst
    int tfBlocks  = ((N + 3) / 4 * 16 + 255) / 256;      // 4 nodes per thread
    agg_kernel<<<aggBlocks, 256, 0, stream>>>(hA, rowstartR, esort, means, N);
    transform_kernel<<<tfBlocks, 256, 0, stream>>>(hA, means, w1root, w1rel, b1, hB, N);
    agg_kernel<<<aggBlocks, 256, 0, stream>>>(hB, rowstartR, esort, means, N);
    transform_kernel<<<tfBlocks, 256, 0, stream>>>(hB, means, w2root, w2rel, b2, hA, N);

    pool_kernel<<<(G * 64 + 255) / 256, 256, 0, stream>>>(hA, batch, linw, linb, out, N, G);
}

// Round 10
// 339.711 us; speedup vs baseline: 1.2463x; 1.0278x over previous
//
#include <hip/hip_runtime.h>

#define CHUNK 2048

// Fused: embed blocks [0,embed_blocks) + per-chunk bucket histogram blocks.
__global__ __launch_bounds__(256) void embed_count_kernel(
    const int* __restrict__ x, const float* __restrict__ emb, float* __restrict__ h0,
    const int* __restrict__ ei, int* __restrict__ pcount,
    int n_nodes, int n_edges, int n_bkt, int embed_blocks)
{
    __shared__ int cnt[512];
    int t = threadIdx.x;
    if ((int)blockIdx.x < embed_blocks) {
        int tt = blockIdx.x * 256 + t;
        if (tt < n_nodes * 16) {
            int n = tt >> 4, q = tt & 15;
            int xv = x[n];
            float4 v = {0.f, 0.f, 0.f, 0.f};
            if (xv != 0) v = *(const float4*)(emb + (size_t)xv * 64 + q * 4);
            *(float4*)(h0 + (size_t)n * 64 + q * 4) = v;
        }
        return;
    }
    int jb = blockIdx.x - embed_blocks;
    for (int b = t; b < 512; b += 256) cnt[b] = 0;
    __syncthreads();
    int base = jb * CHUNK;
#pragma unroll
    for (int i = 0; i < CHUNK / 256; ++i) {
        int e = base + i * 256 + t;
        if (e < n_edges) atomicAdd(&cnt[ei[n_edges + e] >> 7], 1);
    }
    __syncthreads();
    for (int b = t; b < n_bkt; b += 256) pcount[jb * n_bkt + b] = cnt[b];
}

// one block per bucket: exclusive scan over chunk counts -> pre, totals
__global__ __launch_bounds__(256) void colscan_kernel(
    const int* __restrict__ pcount, int* __restrict__ pre,
    int* __restrict__ totals, int* __restrict__ rowstartR,
    int n_chk, int n_bkt, int n_edges, int n_nodes)
{
    __shared__ int ps[256];
    int b = blockIdx.x, t = threadIdx.x;
    if (b == 0 && t == 0) rowstartR[4 * n_nodes] = n_edges;
    int v[4], s = 0;
#pragma unroll
    for (int i = 0; i < 4; ++i) {
        int jj = t * 4 + i;
        v[i] = (jj < n_chk) ? pcount[jj * n_bkt + b] : 0;
        s += v[i];
    }
    ps[t] = s;
    __syncthreads();
    for (int o = 1; o < 256; o <<= 1) {
        int u = (t >= o) ? ps[t - o] : 0;
        __syncthreads();
        ps[t] += u;
        __syncthreads();
    }
    int run = (t > 0) ? ps[t - 1] : 0;
#pragma unroll
    for (int i = 0; i < 4; ++i) {
        int jj = t * 4 + i;
        if (jj < n_chk) pre[jj * n_bkt + b] = run;
        run += v[i];
    }
    if (t == 255) totals[b] = run;
}

// 611 blocks x 2048 edges. Each block re-derives bucket_start locally (scan of
// totals in LDS), adds its own pre row -> deterministic bases, LDS fill
// atomics only. Block 0 publishes bucket_start for the sort kernel.
// Payload: src(16) | r<<16 | dstlo<<18.
__global__ __launch_bounds__(256) void scatter_kernel(
    const int* __restrict__ ei, const int* __restrict__ et,
    const int* __restrict__ pre, const int* __restrict__ totals,
    int* __restrict__ esort, int* __restrict__ bucket_start,
    int n_edges, int n_bkt)
{
    __shared__ int bs[512], fill2[512], ps[256];
    int t = threadIdx.x, j = blockIdx.x;
    int a0 = (2 * t < n_bkt) ? totals[2 * t] : 0;
    int a1 = (2 * t + 1 < n_bkt) ? totals[2 * t + 1] : 0;
    ps[t] = a0 + a1;
    __syncthreads();
    for (int o = 1; o < 256; o <<= 1) {
        int u = (t >= o) ? ps[t - o] : 0;
        __syncthreads();
        ps[t] += u;
        __syncthreads();
    }
    int basex = (t > 0) ? ps[t - 1] : 0;
    bs[2 * t] = basex;
    bs[2 * t + 1] = basex + a0;
    fill2[t] = 0; fill2[t + 256] = 0;
    __syncthreads();
    if (j == 0) {
        for (int b = t; b < n_bkt; b += 256) bucket_start[b] = bs[b];
        if (t == 0) bucket_start[n_bkt] = n_edges;
    }
    for (int b = t; b < n_bkt; b += 256) bs[b] += pre[j * n_bkt + b];
    __syncthreads();
    int base = j * CHUNK;
#pragma unroll
    for (int i = 0; i < CHUNK / 256; ++i) {
        int e = base + i * 256 + t;
        if (e < n_edges) {
            int s = ei[e], d = ei[n_edges + e], r = et[e];
            int b = d >> 7;
            int pos = bs[b] + atomicAdd(&fill2[b], 1);
            esort[pos] = s | (r << 16) | ((d & 127) << 18);
        }
    }
}

// one block per bucket: 512-bin counting sort (bin = dstlo*4 + r),
// emits rowstartR[dst*4 + r].
__global__ __launch_bounds__(256) void bucket_sort_kernel(
    const int* __restrict__ bucket_start, int* __restrict__ esort,
    int* __restrict__ scratch, int* __restrict__ rowstartR, int n_nodes)
{
    __shared__ int cnt[512], off[512], fill[512], ps[256];
    int t = threadIdx.x, b = blockIdx.x;
    int s = bucket_start[b], e = bucket_start[b + 1];
    cnt[t] = 0; cnt[t + 256] = 0; fill[t] = 0; fill[t + 256] = 0;
    __syncthreads();
    int* scr = scratch + (size_t)b * 8192;
    for (int i = s + t; i < e; i += 256) {
        int p = esort[i];
        scr[i - s] = p;
        atomicAdd(&cnt[(p >> 16) & 0x1FF], 1);
    }
    __syncthreads();
    int a0 = cnt[2 * t], a1 = cnt[2 * t + 1];
    ps[t] = a0 + a1;
    __syncthreads();
    for (int o = 1; o < 256; o <<= 1) {
        int v = (t >= o) ? ps[t - o] : 0;
        __syncthreads();
        ps[t] += v;
        __syncthreads();
    }
    int basex = (t > 0) ? ps[t - 1] : 0;
    off[2 * t] = basex;
    off[2 * t + 1] = basex + a0;
    __syncthreads();
    int d0 = b * 128 + (2 * t >> 2);
    if (d0 < n_nodes) rowstartR[b * 512 + 2 * t] = s + off[2 * t];
    int d1 = b * 128 + ((2 * t + 1) >> 2);
    if (d1 < n_nodes) rowstartR[b * 512 + 2 * t + 1] = s + off[2 * t + 1];
    __syncthreads();
    for (int i = s + t; i < e; i += 256) {
        int p = scr[i - s];
        int bin = (p >> 16) & 0x1FF;
        int pos = s + off[bin] + atomicAdd(&fill[bin], 1);
        esort[pos] = p;
    }
}

// one wave per dst; rel-grouped sub-ranges; quarter-wave handles edge PAIRS
// (2 independent row-loads in flight per iteration).
__global__ __launch_bounds__(256) void agg_kernel(
    const float* __restrict__ hin, const int* __restrict__ rowstartR,
    const int* __restrict__ esort, float* __restrict__ means, int n_nodes)
{
    int wid = (blockIdx.x * 256 + threadIdx.x) >> 6;
    int lane = threadIdx.x & 63;
    if (wid >= n_nodes) return;
    int q = lane >> 4;
    int c = lane & 15;
    int4 rs = *(const int4*)(rowstartR + wid * 4);

#pragma unroll
    for (int r = 0; r < 3; ++r) {
        int sR = (r == 0) ? rs.x : (r == 1) ? rs.y : rs.z;
        int eR = (r == 0) ? rs.y : (r == 1) ? rs.z : rs.w;
        float4 a = {0.f, 0.f, 0.f, 0.f};
        float4 b = {0.f, 0.f, 0.f, 0.f};
        int i = sR + 2 * q;
        for (; i + 2 <= eR; i += 8) {
            int p0 = esort[i];
            int p1 = esort[i + 1];
            float4 v0 = *(const float4*)(hin + (size_t)(p0 & 0xFFFF) * 64 + c * 4);
            float4 v1 = *(const float4*)(hin + (size_t)(p1 & 0xFFFF) * 64 + c * 4);
            a.x += v0.x; a.y += v0.y; a.z += v0.z; a.w += v0.w;
            b.x += v1.x; b.y += v1.y; b.z += v1.z; b.w += v1.w;
        }
        if (i < eR) {   // odd tail: i == eR-1
            int p0 = esort[i];
            float4 v0 = *(const float4*)(hin + (size_t)(p0 & 0xFFFF) * 64 + c * 4);
            a.x += v0.x; a.y += v0.y; a.z += v0.z; a.w += v0.w;
        }
        a.x += b.x; a.y += b.y; a.z += b.z; a.w += b.w;
        a.x += __shfl_xor(a.x, 16); a.y += __shfl_xor(a.y, 16);
        a.z += __shfl_xor(a.z, 16); a.w += __shfl_xor(a.w, 16);
        a.x += __shfl_xor(a.x, 32); a.y += __shfl_xor(a.y, 32);
        a.z += __shfl_xor(a.z, 32); a.w += __shfl_xor(a.w, 32);
        if (q == r) {
            float inv = 1.f / (float)max(eR - sR, 1);
            float4 m = {a.x * inv, a.y * inv, a.z * inv, a.w * inv};
            *(float4*)(means + (size_t)wid * 192 + r * 64 + c * 4) = m;
        }
    }
}

// thread = (4-node group, j-quad). W streamed through LDS in 4 slabs of 64
// rows (16 KB), double-buffered (32 KB -> 5 blocks/CU).
__global__ __launch_bounds__(256) void transform_kernel(
    const float* __restrict__ hin, const float* __restrict__ means,
    const float* __restrict__ wroot, const float* __restrict__ wrel,
    const float* __restrict__ bias, float* __restrict__ hout, int n_nodes)
{
    __shared__ float wsh[2][4096];   // 2 x 16 KB
    int t = threadIdx.x;
    int gt = blockIdx.x * 256 + t;
    int g = gt >> 4, q = gt & 15;
    int n0 = g * 4;
    bool active = (n0 < n_nodes);

    {
        const float4* sp = (const float4*)wroot;
        float4* d = (float4*)wsh[0];
#pragma unroll
        for (int i = 0; i < 4; ++i) d[t + i * 256] = sp[t + i * 256];
    }

    float4 acc[4];
    float4 b = {0.f, 0.f, 0.f, 0.f};
    if (active) b = *(const float4*)(bias + q * 4);
#pragma unroll
    for (int i = 0; i < 4; ++i) acc[i] = b;

    const float* hv = hin + (size_t)n0 * 64;
    const float* mv = means + (size_t)n0 * 192;

    for (int s = 0; s < 4; ++s) {
        __syncthreads();
        if (s < 3) {
            const float4* sp = (const float4*)wrel + (size_t)s * 1024;
            float4* d = (float4*)wsh[(s + 1) & 1];
#pragma unroll
            for (int i = 0; i < 4; ++i) d[t + i * 256] = sp[t + i * 256];
        }
        const float* vbase = (s == 0) ? hv : (mv + (s - 1) * 64);
        int vstride = (s == 0) ? 64 : 192;
        const float* wbuf = wsh[s & 1];
        if (active) {
#pragma unroll 4
            for (int k4 = 0; k4 < 16; ++k4) {
                float4 v[4];
#pragma unroll
                for (int i = 0; i < 4; ++i)
                    v[i] = *(const float4*)(vbase + i * vstride + k4 * 4);
#pragma unroll
                for (int kk = 0; kk < 4; ++kk) {
                    float4 w = *(const float4*)(wbuf + (k4 * 4 + kk) * 64 + q * 4);
#pragma unroll
                    for (int i = 0; i < 4; ++i) {
                        float sv = kk == 0 ? v[i].x : kk == 1 ? v[i].y : kk == 2 ? v[i].z : v[i].w;
                        acc[i].x = fmaf(sv, w.x, acc[i].x);
                        acc[i].y = fmaf(sv, w.y, acc[i].y);
                        acc[i].z = fmaf(sv, w.z, acc[i].z);
                        acc[i].w = fmaf(sv, w.w, acc[i].w);
                    }
                }
            }
        }
    }
    if (active) {
        float* o = hout + (size_t)n0 * 64 + q * 4;
#pragma unroll
        for (int i = 0; i < 4; ++i) {
            float4 r = {fmaxf(acc[i].x, 0.f), fmaxf(acc[i].y, 0.f),
                        fmaxf(acc[i].z, 0.f), fmaxf(acc[i].w, 0.f)};
            *(float4*)(o + i * 64) = r;
        }
    }
}

// wave per graph: batch sorted -> binary-search bounds, mean, then 64->2 head
__global__ __launch_bounds__(256) void pool_kernel(
    const float* __restrict__ h2, const int* __restrict__ batch,
    const float* __restrict__ linw, const float* __restrict__ linb,
    float* __restrict__ out, int n_nodes, int n_graphs)
{
    int wid = (blockIdx.x * 256 + threadIdx.x) >> 6;
    int lane = threadIdx.x & 63;
    if (wid >= n_graphs) return;
    int g = wid;
    int lo = 0, hi = n_nodes;
    while (lo < hi) { int mid = (lo + hi) >> 1; if (batch[mid] < g) lo = mid + 1; else hi = mid; }
    int s = lo;
    lo = 0; hi = n_nodes;
    while (lo < hi) { int mid = (lo + hi) >> 1; if (batch[mid] < g + 1) lo = mid + 1; else hi = mid; }
    int e = lo;
    float sum = 0.f;
    for (int n = s; n < e; ++n) sum += h2[(size_t)n * 64 + lane];
    float mean = sum / (float)max(e - s, 1);
    float d0 = mean * linw[lane * 2 + 0];
    float d1 = mean * linw[lane * 2 + 1];
    for (int off = 32; off > 0; off >>= 1) {
        d0 += __shfl_down(d0, off);
        d1 += __shfl_down(d1, off);
    }
    if (lane == 0) {
        out[g * 2 + 0] = d0 + linb[0];
        out[g * 2 + 1] = d1 + linb[1];
    }
}

extern "C" void kernel_launch(void* const* d_in, const int* in_sizes, int n_in,
                              void* d_out, int out_size, void* d_ws, size_t ws_size,
                              hipStream_t stream)
{
    const int*   x      = (const int*)d_in[0];
    const int*   ei     = (const int*)d_in[1];
    const int*   et     = (const int*)d_in[2];
    const int*   batch  = (const int*)d_in[3];
    const float* emb    = (const float*)d_in[4];
    const float* w1rel  = (const float*)d_in[5];
    const float* w1root = (const float*)d_in[6];
    const float* b1     = (const float*)d_in[7];
    const float* w2rel  = (const float*)d_in[8];
    const float* w2root = (const float*)d_in[9];
    const float* b2     = (const float*)d_in[10];
    const float* linw   = (const float*)d_in[11];
    const float* linb   = (const float*)d_in[12];
    float* out = (float*)d_out;

    const int N = in_sizes[0];            // 50000
    const int E = in_sizes[2];            // 1250000
    const int G = out_size / 2;           // 512
    const int NBKT = (N + 127) >> 7;      // 391
    const int NCHK = (E + CHUNK - 1) / CHUNK;  // 611

    // workspace layout (~70 MB); pcount/pre live inside the means region
    // (beyond the 12.8 MB sort-scratch prefix), consumed before agg writes it.
    float* hA        = (float*)d_ws;                     // [N][64]
    float* hB        = hA + (size_t)N * 64;              // [N][64]
    float* means     = hB + (size_t)N * 64;              // [N][192]
    int*   esort     = (int*)(means + (size_t)N * 192);  // [E]
    int*   rowstartR = esort + E;                        // [4N+4]
    int*   bucket_start = rowstartR + 4 * N + 4;         // [NBKT+1]
    int*   totals    = bucket_start + NBKT + 1;          // [NBKT]
    int*   scratch   = (int*)means;                      // sort scratch (12.8 MB)
    int*   pcount    = (int*)means + 4 * 1024 * 1024;    // [NCHK*NBKT] (~1 MB)
    int*   pre       = (int*)means + 5 * 1024 * 1024;    // [NCHK*NBKT]

    int embedBlocks = (N * 16 + 255) / 256;              // 3125
    embed_count_kernel<<<embedBlocks + NCHK, 256, 0, stream>>>(
        x, emb, hA, ei, pcount, N, E, NBKT, embedBlocks);
    colscan_kernel<<<NBKT, 256, 0, stream>>>(pcount, pre, totals, rowstartR, NCHK, NBKT, E, N);
    scatter_kernel<<<NCHK, 256, 0, stream>>>(ei, et, pre, totals, esort, bucket_start, E, NBKT);
    bucket_sort_kernel<<<NBKT, 256, 0, stream>>>(bucket_start, esort, scratch, rowstartR, N);

    int aggBlocks = (N * 64 + 255) / 256;                // one wave per dst
    int tfBlocks  = ((N + 3) / 4 * 16 + 255) / 256;      // 4 nodes per thread
    agg_kernel<<<aggBlocks, 256, 0, stream>>>(hA, rowstartR, esort, means, N);
    transform_kernel<<<tfBlocks, 256, 0, stream>>>(hA, means, w1root, w1rel, b1, hB, N);
    agg_kernel<<<aggBlocks, 256, 0, stream>>>(hB, rowstartR, esort, means, N);
    transform_kernel<<<tfBlocks, 256, 0, stream>>>(hB, means, w2root, w2rel, b2, hA, N);

    pool_kernel<<<(G * 64 + 255) / 256, 256, 0, stream>>>(hA, batch, linw, linb, out, N, G);
}